// Round 17
// baseline (271.184 us; speedup 1.0000x reference)
//
#include <hip/hip_runtime.h>
#include <hip/hip_fp8.h>
#include <math.h>

#define MAXNB 512
#define CHUNK 4096

typedef float floatx2 __attribute__((ext_vector_type(2)));

#if __has_builtin(__builtin_amdgcn_cvt_pk_f32_fp8)
__device__ inline floatx2 fp8pair(unsigned short u) {
    return __builtin_amdgcn_cvt_pk_f32_fp8((unsigned)u, false);
}
#else
__device__ inline floatx2 fp8pair(unsigned short u) {
    __hip_fp8_e4m3 a, b;
    a.__x = (__hip_fp8_storage_t)(u & 0xff);
    b.__x = (__hip_fp8_storage_t)(u >> 8);
    floatx2 r; r.x = (float)a; r.y = (float)b; return r;
}
#endif
__device__ inline unsigned char f2fp8(float f) {
    __hip_fp8_e4m3 q(f); return (unsigned char)q.__x;
}

// ---------------- utility ----------------

__global__ void copy_kernel(const float4* __restrict__ src, float4* __restrict__ dst, int n4) {
    int tid = blockIdx.x * blockDim.x + threadIdx.x;
    int stride = gridDim.x * blockDim.x;
    for (int i = tid; i < n4; i += stride) dst[i] = src[i];
}

// ---------------- binned CSR build ----------------

__global__ void binhist_kernel(const int* __restrict__ dst, int* __restrict__ binCnt,
                               int E, int NB) {
    __shared__ int h[MAXNB];
    for (int i = threadIdx.x; i < NB; i += blockDim.x) h[i] = 0;
    __syncthreads();
    int tid = blockIdx.x * blockDim.x + threadIdx.x;
    int stride = gridDim.x * blockDim.x;
    for (int e = tid; e < E; e += stride) atomicAdd(&h[dst[e] >> 8], 1);
    __syncthreads();
    for (int i = threadIdx.x; i < NB; i += blockDim.x) {
        int v = h[i];
        if (v) atomicAdd(&binCnt[i], v);
    }
}

__global__ void binscan_kernel(const int* __restrict__ binCnt, int* __restrict__ binBase,
                               int* __restrict__ binCursor, int* __restrict__ rowptr,
                               int NB, int N, int E) {
    int lane = threadIdx.x;
    int running = 0;
    for (int c = 0; c * 64 < NB; ++c) {
        int idx = c * 64 + lane;
        int v = (idx < NB) ? binCnt[idx] : 0;
        int inc = v;
        for (int off = 1; off < 64; off <<= 1) {
            int u = __shfl_up(inc, off);
            if (lane >= off) inc += u;
        }
        int excl = running + inc - v;
        if (idx < NB) { binBase[idx] = excl; binCursor[idx] = excl; }
        running += __shfl(inc, 63);
    }
    if (lane == 0) { binBase[NB] = E; rowptr[N] = E; }
}

__launch_bounds__(256, 4)
__global__ void phaseB_kernel(const int* __restrict__ src, const int* __restrict__ dst,
                              int* __restrict__ binCursor, int2* __restrict__ etmp,
                              int E, int NB) {
    __shared__ int hist[MAXNB], sbase[MAXNB], lcnt[MAXNB], adj[MAXNB];
    __shared__ int2 rb[CHUNK];
    int t = threadIdx.x, lane = t & 63, wv = t >> 6;
    int base = blockIdx.x * CHUNK;
    int ne = min(CHUNK, E - base);
    for (int i = t; i < NB; i += 256) { hist[i] = 0; lcnt[i] = 0; }
    __syncthreads();
    const int PT = CHUNK / 256;
    int rs[PT], rd[PT];
#pragma unroll
    for (int i = 0; i < PT; ++i) {
        int idx = i * 256 + t;
        if (idx < ne) {
            rs[i] = src[base + idx];
            rd[i] = dst[base + idx];
            atomicAdd(&hist[rd[i] >> 8], 1);
        } else rd[i] = -1;
    }
    __syncthreads();
    if (wv == 0) {
        int running = 0;
        for (int c = 0; c * 64 < NB; ++c) {
            int idx = c * 64 + lane;
            int v = (idx < NB) ? hist[idx] : 0;
            int inc = v;
            for (int off = 1; off < 64; off <<= 1) {
                int u = __shfl_up(inc, off);
                if (lane >= off) inc += u;
            }
            if (idx < NB) sbase[idx] = running + inc - v;
            running += __shfl(inc, 63);
        }
    }
    __syncthreads();
    for (int bIdx = t; bIdx < NB; bIdx += 256) {
        int hcount = hist[bIdx];
        if (hcount) {
            int g = atomicAdd(&binCursor[bIdx], hcount);
            adj[bIdx] = g - sbase[bIdx];
        }
    }
    __syncthreads();
#pragma unroll
    for (int i = 0; i < PT; ++i) {
        if (rd[i] >= 0) {
            int bb = rd[i] >> 8;
            int off = atomicAdd(&lcnt[bb], 1);
            rb[sbase[bb] + off] = make_int2(rs[i], rd[i]);
        }
    }
    __syncthreads();
    for (int p = t; p < ne; p += 256) {
        int2 v = rb[p];
        etmp[p + adj[v.y >> 8]] = v;
    }
}

__global__ void bin2csr_kernel(const int2* __restrict__ etmp, const int* __restrict__ binBase,
                               int* __restrict__ rowptr, float* __restrict__ dinv,
                               int* __restrict__ esrc, int N) {
    __shared__ int hist[256], lcur[256], wsum[4];
    int t = threadIdx.x, b = blockIdx.x;
    hist[t] = 0;
    __syncthreads();
    int bb = binBase[b], ne = binBase[b + 1] - bb;
    for (int i = t; i < ne; i += 256) atomicAdd(&hist[etmp[bb + i].y & 255], 1);
    __syncthreads();
    int lane = t & 63, wv = t >> 6;
    int v = hist[t];
    int inc = v;
    for (int off = 1; off < 64; off <<= 1) {
        int u = __shfl_up(inc, off);
        if (lane >= off) inc += u;
    }
    if (lane == 63) wsum[wv] = inc;
    __syncthreads();
    int woff = 0;
    for (int i = 0; i < wv; ++i) woff += wsum[i];
    int excl = woff + inc - v;
    int node = b * 256 + t;
    if (node < N) {
        rowptr[node] = bb + excl;
        dinv[node] = rsqrtf((float)(v + 1));   // +1 self loop
    }
    lcur[t] = excl;
    __syncthreads();
    for (int i = t; i < ne; i += 256) {
        int2 e = etmp[bb + i];
        int p = atomicAdd(&lcur[e.y & 255], 1);
        esrc[bb + p] = e.x;
    }
}

// ---------------- layer kernels ----------------

// Apb[N,64](fp8 e4m3) = (X[N,128] @ W1) * dinv[row]; W1 column in 128 regs.
// 2 rows per wave per iteration, next-pair global prefetch.
__launch_bounds__(256, 2)
__global__ void rowgemm_kernel(const float* __restrict__ X, const float* __restrict__ W,
                               const float* __restrict__ dinv,
                               unsigned char* __restrict__ Apb, int N) {
    __shared__ float xbuf[4][2][128];
    int lane = threadIdx.x & 63;
    int wv = threadIdx.x >> 6;
    float w[128];
#pragma unroll
    for (int k = 0; k < 128; ++k) w[k] = W[k * 64 + lane];
    int wave = (blockIdx.x * blockDim.x + threadIdx.x) >> 6;
    int nw = (gridDim.x * blockDim.x) >> 6;
    const float4* xa4 = (const float4*)xbuf[wv][0];
    const float4* xb4 = (const float4*)xbuf[wv][1];
    int v = wave * 2;
    int stride = nw * 2;
    float2 x2a = make_float2(0.f, 0.f), x2b = make_float2(0.f, 0.f);
    if (v < N)     x2a = *(const float2*)(X + (size_t)v * 128 + lane * 2);
    if (v + 1 < N) x2b = *(const float2*)(X + (size_t)(v + 1) * 128 + lane * 2);
    while (v < N) {
        *(float2*)&xbuf[wv][0][lane * 2] = x2a;
        *(float2*)&xbuf[wv][1][lane * 2] = x2b;
        int vn = v + stride;
        float2 xna = make_float2(0.f, 0.f), xnb = make_float2(0.f, 0.f);
        if (vn < N)     xna = *(const float2*)(X + (size_t)vn * 128 + lane * 2);
        if (vn + 1 < N) xnb = *(const float2*)(X + (size_t)(vn + 1) * 128 + lane * 2);
        float dva = dinv[v];
        float dvb = (v + 1 < N) ? dinv[v + 1] : 0.f;
        asm volatile("s_waitcnt lgkmcnt(0)" ::: "memory");
        float acca = 0.f, accb = 0.f;
#pragma unroll
        for (int k4 = 0; k4 < 32; ++k4) {
            float4 va = xa4[k4];
            float4 vb = xb4[k4];
            float w0 = w[4 * k4 + 0], w1 = w[4 * k4 + 1];
            float w2 = w[4 * k4 + 2], w3 = w[4 * k4 + 3];
            acca += va.x * w0 + va.y * w1 + va.z * w2 + va.w * w3;
            accb += vb.x * w0 + vb.y * w1 + vb.z * w2 + vb.w * w3;
        }
        Apb[(size_t)v * 64 + lane] = f2fp8(acca * dva);
        if (v + 1 < N) Apb[(size_t)(v + 1) * 64 + lane] = f2fp8(accb * dvb);
        asm volatile("s_waitcnt lgkmcnt(0)" ::: "memory");
        v = vn; x2a = xna; x2b = xnb;
    }
}

// Wave per 2 nodes: merged scalar-indexed paired gather (2 row-loads in flight
// per iter x unroll 2), single fold pass, parallel h staging (half0 -> node0
// slot, half1 -> node1 slot), dual-accumulator GEMM2 (ILP 2) -> A2pb (64B).
__launch_bounds__(256, 2)
__global__ void layer_mid_kernel(const unsigned char* __restrict__ Apb,
                                 const int* __restrict__ esrc,
                                 const int* __restrict__ rowptr, const float* __restrict__ dinv,
                                 const float* __restrict__ W2, const float* __restrict__ b1,
                                 unsigned char* __restrict__ A2pb, int N) {
    __shared__ float hbuf[4][2][64];
    int lane = threadIdx.x & 63;
    int wv = threadIdx.x >> 6;
    int pl = lane & 31, half = lane >> 5;
    int cidx = lane < 40 ? lane : 0;
    float w2[64];
#pragma unroll
    for (int k = 0; k < 64; ++k) w2[k] = W2[k * 40 + cidx];
    float2 bias2 = ((const float2*)b1)[pl];
    int wave = (blockIdx.x * blockDim.x + threadIdx.x) >> 6;
    int nw = (gridDim.x * blockDim.x) >> 6;
    const float4* hb0 = (const float4*)hbuf[wv][0];
    const float4* hb1 = (const float4*)hbuf[wv][1];
    for (int v0 = wave * 2; v0 < N; v0 += nw * 2) {
        bool has1 = (v0 + 1 < N);
        int v1 = has1 ? v0 + 1 : v0;
        int i0a = __builtin_amdgcn_readfirstlane(rowptr[v0]);
        int i1a = __builtin_amdgcn_readfirstlane(rowptr[v0 + 1]);
        int i1b = has1 ? __builtin_amdgcn_readfirstlane(rowptr[v0 + 2]) : i1a;
        int i0b = i1a;
        float ax0 = 0.f, ay0 = 0.f, ax1 = 0.f, ay1 = 0.f;
        int ja = i0a, jb = i0b;
#pragma unroll 2
        for (; ja + 2 <= i1a && jb + 2 <= i1b; ja += 2, jb += 2) {
            int sa0 = esrc[ja], sa1 = esrc[ja + 1];
            int sb0 = esrc[jb], sb1 = esrc[jb + 1];
            int sa = half ? sa1 : sa0;
            int sb = half ? sb1 : sb0;
            unsigned short ua = *(const unsigned short*)(Apb + (size_t)sa * 64 + pl * 2);
            unsigned short ub = *(const unsigned short*)(Apb + (size_t)sb * 64 + pl * 2);
            floatx2 fa = fp8pair(ua), fb = fp8pair(ub);
            ax0 += fa.x; ay0 += fa.y;
            ax1 += fb.x; ay1 += fb.y;
        }
#pragma unroll 2
        for (; ja + 2 <= i1a; ja += 2) {
            int sa0 = esrc[ja], sa1 = esrc[ja + 1];
            int sa = half ? sa1 : sa0;
            unsigned short ua = *(const unsigned short*)(Apb + (size_t)sa * 64 + pl * 2);
            floatx2 fa = fp8pair(ua);
            ax0 += fa.x; ay0 += fa.y;
        }
        if (ja < i1a && half == 0) {
            unsigned short ua = *(const unsigned short*)(Apb + (size_t)esrc[ja] * 64 + pl * 2);
            floatx2 fa = fp8pair(ua);
            ax0 += fa.x; ay0 += fa.y;
        }
#pragma unroll 2
        for (; jb + 2 <= i1b; jb += 2) {
            int sb0 = esrc[jb], sb1 = esrc[jb + 1];
            int sb = half ? sb1 : sb0;
            unsigned short ub = *(const unsigned short*)(Apb + (size_t)sb * 64 + pl * 2);
            floatx2 fb = fp8pair(ub);
            ax1 += fb.x; ay1 += fb.y;
        }
        if (jb < i1b && half == 0) {
            unsigned short ub = *(const unsigned short*)(Apb + (size_t)esrc[jb] * 64 + pl * 2);
            floatx2 fb = fp8pair(ub);
            ax1 += fb.x; ay1 += fb.y;
        }
        ax0 += __shfl_xor(ax0, 32); ay0 += __shfl_xor(ay0, 32);
        ax1 += __shfl_xor(ax1, 32); ay1 += __shfl_xor(ay1, 32);
        float dv0 = dinv[v0], dv1 = dinv[v1];
        unsigned short us0 = *(const unsigned short*)(Apb + (size_t)v0 * 64 + pl * 2);
        unsigned short us1 = *(const unsigned short*)(Apb + (size_t)v1 * 64 + pl * 2);
        floatx2 fs0 = fp8pair(us0), fs1 = fp8pair(us1);
        float h00 = dv0 * (ax0 + fs0.x * dv0) + bias2.x;
        float h01 = dv0 * (ay0 + fs0.y * dv0) + bias2.y;
        float h10 = dv1 * (ax1 + fs1.x * dv1) + bias2.x;
        float h11 = dv1 * (ay1 + fs1.y * dv1) + bias2.y;
        h00 = h00 > 0.f ? h00 : 0.f;
        h01 = h01 > 0.f ? h01 : 0.f;
        h10 = h10 > 0.f ? h10 : 0.f;
        h11 = h11 > 0.f ? h11 : 0.f;
        // parallel staging: half0 lanes write node0 slot, half1 lanes node1 slot
        if (half == 0) *(float2*)&hbuf[wv][0][pl * 2] = make_float2(h00, h01);
        else           *(float2*)&hbuf[wv][1][pl * 2] = make_float2(h10, h11);
        asm volatile("s_waitcnt lgkmcnt(0)" ::: "memory");
        float a20 = 0.f, a21 = 0.f;
#pragma unroll
        for (int k4 = 0; k4 < 16; ++k4) {
            float4 h0 = hb0[k4];
            float4 h1 = hb1[k4];
            float w0 = w2[4 * k4 + 0], w1 = w2[4 * k4 + 1];
            float w2c = w2[4 * k4 + 2], w3 = w2[4 * k4 + 3];
            a20 += h0.x * w0 + h0.y * w1 + h0.z * w2c + h0.w * w3;
            a21 += h1.x * w0 + h1.y * w1 + h1.z * w2c + h1.w * w3;
        }
        if (lane < 40) {
            A2pb[(size_t)v0 * 64 + lane] = f2fp8(a20 * dv0);
            if (has1) A2pb[(size_t)v1 * 64 + lane] = f2fp8(a21 * dv1);
        }
        asm volatile("s_waitcnt lgkmcnt(0)" ::: "memory");
    }
}

// Wave per 2 nodes: merged paired gather over 40 fp8 cols (64B stride),
// two interleaved softmax chains; half0 writes node0, half1 writes node1.
__global__ void layer_out_kernel(const unsigned char* __restrict__ A2pb,
                                 const int* __restrict__ esrc,
                                 const int* __restrict__ rowptr, const float* __restrict__ dinv,
                                 const float* __restrict__ b2, float* __restrict__ out, int N) {
    int lane = threadIdx.x & 63;
    int pl = lane & 31, half = lane >> 5;
    bool pact = pl < 20;
    int plc = pact ? pl : 0;
    float2 b2v = ((const float2*)b2)[plc];
    int wave = (blockIdx.x * blockDim.x + threadIdx.x) >> 6;
    int nw = (gridDim.x * blockDim.x) >> 6;
    for (int v0 = wave * 2; v0 < N; v0 += nw * 2) {
        bool has1 = (v0 + 1 < N);
        int v1 = has1 ? v0 + 1 : v0;
        int i0a = __builtin_amdgcn_readfirstlane(rowptr[v0]);
        int i1a = __builtin_amdgcn_readfirstlane(rowptr[v0 + 1]);
        int i1b = has1 ? __builtin_amdgcn_readfirstlane(rowptr[v0 + 2]) : i1a;
        int i0b = i1a;
        float ax0 = 0.f, ay0 = 0.f, ax1 = 0.f, ay1 = 0.f;
        int ja = i0a, jb = i0b;
#pragma unroll 2
        for (; ja + 2 <= i1a && jb + 2 <= i1b; ja += 2, jb += 2) {
            int sa0 = esrc[ja], sa1 = esrc[ja + 1];
            int sb0 = esrc[jb], sb1 = esrc[jb + 1];
            int sa = half ? sa1 : sa0;
            int sb = half ? sb1 : sb0;
            if (pact) {
                unsigned short ua = *(const unsigned short*)(A2pb + (size_t)sa * 64 + pl * 2);
                unsigned short ub = *(const unsigned short*)(A2pb + (size_t)sb * 64 + pl * 2);
                floatx2 fa = fp8pair(ua), fb = fp8pair(ub);
                ax0 += fa.x; ay0 += fa.y;
                ax1 += fb.x; ay1 += fb.y;
            }
        }
#pragma unroll 2
        for (; ja + 2 <= i1a; ja += 2) {
            int sa0 = esrc[ja], sa1 = esrc[ja + 1];
            int sa = half ? sa1 : sa0;
            if (pact) {
                unsigned short ua = *(const unsigned short*)(A2pb + (size_t)sa * 64 + pl * 2);
                floatx2 fa = fp8pair(ua);
                ax0 += fa.x; ay0 += fa.y;
            }
        }
        if (ja < i1a && half == 0 && pact) {
            unsigned short ua = *(const unsigned short*)(A2pb + (size_t)esrc[ja] * 64 + pl * 2);
            floatx2 fa = fp8pair(ua);
            ax0 += fa.x; ay0 += fa.y;
        }
#pragma unroll 2
        for (; jb + 2 <= i1b; jb += 2) {
            int sb0 = esrc[jb], sb1 = esrc[jb + 1];
            int sb = half ? sb1 : sb0;
            if (pact) {
                unsigned short ub = *(const unsigned short*)(A2pb + (size_t)sb * 64 + pl * 2);
                floatx2 fb = fp8pair(ub);
                ax1 += fb.x; ay1 += fb.y;
            }
        }
        if (jb < i1b && half == 0 && pact) {
            unsigned short ub = *(const unsigned short*)(A2pb + (size_t)esrc[jb] * 64 + pl * 2);
            floatx2 fb = fp8pair(ub);
            ax1 += fb.x; ay1 += fb.y;
        }
        ax0 += __shfl_xor(ax0, 32); ay0 += __shfl_xor(ay0, 32);
        ax1 += __shfl_xor(ax1, 32); ay1 += __shfl_xor(ay1, 32);
        float dv0 = dinv[v0], dv1 = dinv[v1];
        float z00 = -INFINITY, z01 = -INFINITY, z10 = -INFINITY, z11 = -INFINITY;
        if (pact) {
            unsigned short us0 = *(const unsigned short*)(A2pb + (size_t)v0 * 64 + pl * 2);
            unsigned short us1 = *(const unsigned short*)(A2pb + (size_t)v1 * 64 + pl * 2);
            floatx2 fs0 = fp8pair(us0), fs1 = fp8pair(us1);
            z00 = dv0 * (ax0 + fs0.x * dv0) + b2v.x;
            z01 = dv0 * (ay0 + fs0.y * dv0) + b2v.y;
            z10 = dv1 * (ax1 + fs1.x * dv1) + b2v.x;
            z11 = dv1 * (ay1 + fs1.y * dv1) + b2v.y;
        }
        float m0 = fmaxf(z00, z01), m1 = fmaxf(z10, z11);
        for (int off = 16; off; off >>= 1) {
            m0 = fmaxf(m0, __shfl_xor(m0, off));
            m1 = fmaxf(m1, __shfl_xor(m1, off));
        }
        float e00 = pact ? expf(z00 - m0) : 0.f;
        float e01 = pact ? expf(z01 - m0) : 0.f;
        float e10 = pact ? expf(z10 - m1) : 0.f;
        float e11 = pact ? expf(z11 - m1) : 0.f;
        float s0 = e00 + e01, s1 = e10 + e11;
        for (int off = 16; off; off >>= 1) {
            s0 += __shfl_xor(s0, off);
            s1 += __shfl_xor(s1, off);
        }
        float p00 = e00 / s0, p01 = e01 / s0;
        float p10 = e10 / s1, p11 = e11 / s1;
        float n0 = pact ? fmaxf(p00, p01) : -INFINITY;
        float n1 = pact ? fmaxf(p10, p11) : -INFINITY;
        for (int off = 16; off; off >>= 1) {
            n0 = fmaxf(n0, __shfl_xor(n0, off));
            n1 = fmaxf(n1, __shfl_xor(n1, off));
        }
        float q00 = pact ? expf(p00 - n0) : 0.f;
        float q01 = pact ? expf(p01 - n0) : 0.f;
        float q10 = pact ? expf(p10 - n1) : 0.f;
        float q11 = pact ? expf(p11 - n1) : 0.f;
        float t0 = q00 + q01, t1 = q10 + q11;
        for (int off = 16; off; off >>= 1) {
            t0 += __shfl_xor(t0, off);
            t1 += __shfl_xor(t1, off);
        }
        if (pact) {
            if (half == 0) {
                float ls = logf(t0);
                *(float2*)&out[(size_t)v0 * 40 + pl * 2] =
                    make_float2((p00 - n0) - ls, (p01 - n0) - ls);
            } else if (has1) {
                float ls = logf(t1);
                *(float2*)&out[(size_t)v1 * 40 + pl * 2] =
                    make_float2((p10 - n1) - ls, (p11 - n1) - ls);
            }
        }
    }
}

// ---------------- launch ----------------

extern "C" void kernel_launch(void* const* d_in, const int* in_sizes, int n_in,
                              void* d_out, int out_size, void* d_ws, size_t ws_size,
                              hipStream_t stream) {
    const float* x_in  = (const float*)d_in[0];
    const int*   ei    = (const int*)d_in[1];
    const float* W1_in = (const float*)d_in[2];
    const float* b1_in = (const float*)d_in[3];
    const float* W2_in = (const float*)d_in[4];
    const float* b2_in = (const float*)d_in[5];
    float* out = (float*)d_out;

    int N = in_sizes[0] / 128;
    int E = in_sizes[1] / 2;
    const int* src = ei;
    const int* dst = ei + E;
    int NB = (N + 255) >> 8;            // 256-node bins

    char* ws = (char*)d_ws;
    size_t o = 0;
    auto alloc = [&](size_t bytes) { void* p = ws + o; o += (bytes + 255) & ~(size_t)255; return p; };
    int*   binCnt    = (int*)alloc((size_t)MAXNB * 4);
    int*   binBase   = (int*)alloc(((size_t)MAXNB + 1) * 4);
    int*   binCursor = (int*)alloc((size_t)MAXNB * 4);
    float* dinv      = (float*)alloc((size_t)N * 4);
    int*   rowptr    = (int*)alloc(((size_t)N + 1) * 4);
    int2*  etmp      = (int2*)alloc((size_t)E * 8);
    int*   esrc      = (int*)alloc((size_t)E * 4);
    unsigned char* Apb  = (unsigned char*)alloc((size_t)N * 64);
    unsigned char* A2pb = (unsigned char*)alloc((size_t)N * 64);   // 64B row stride (40 used)
    float* W1c = (float*)alloc(128 * 64 * 4);
    float* W2c = (float*)alloc(64 * 40 * 4);
    float* b1c = (float*)alloc(64 * 4);
    float* b2c = (float*)alloc(40 * 4);

    // stage small fp32 params
    copy_kernel<<<8, 256, 0, stream>>>((const float4*)W1_in, (float4*)W1c, 128 * 64 / 4);
    copy_kernel<<<4, 256, 0, stream>>>((const float4*)W2_in, (float4*)W2c, 64 * 40 / 4);
    copy_kernel<<<1, 64, 0, stream>>>((const float4*)b1_in, (float4*)b1c, 16);
    copy_kernel<<<1, 64, 0, stream>>>((const float4*)b2_in, (float4*)b2c, 10);

    // binned CSR build
    hipMemsetAsync(binCnt, 0, (size_t)MAXNB * 4, stream);
    binhist_kernel<<<512, 256, 0, stream>>>(dst, binCnt, E, NB);
    binscan_kernel<<<1, 64, 0, stream>>>(binCnt, binBase, binCursor, rowptr, NB, N, E);
    phaseB_kernel<<<(E + CHUNK - 1) / CHUNK, 256, 0, stream>>>(src, dst, binCursor, etmp, E, NB);
    bin2csr_kernel<<<NB, 256, 0, stream>>>(etmp, binBase, rowptr, dinv, esrc, N);

    // layers
    rowgemm_kernel<<<4096, 256, 0, stream>>>(x_in, W1c, dinv, Apb, N);
    layer_mid_kernel<<<2048, 256, 0, stream>>>(Apb, esrc, rowptr, dinv, W2c, b1c, A2pb, N);
    layer_out_kernel<<<2048, 256, 0, stream>>>(A2pb, esrc, rowptr, dinv, b2c, out, N);
}

// Round 18
// 243.184 us; speedup vs baseline: 1.1151x; 1.1151x over previous
//
#include <hip/hip_runtime.h>
#include <hip/hip_fp8.h>
#include <math.h>

#define MAXNB 512
#define CHUNK 4096

typedef float floatx2 __attribute__((ext_vector_type(2)));

#if __has_builtin(__builtin_amdgcn_cvt_pk_f32_fp8)
__device__ inline floatx2 fp8pair(unsigned short u) {
    return __builtin_amdgcn_cvt_pk_f32_fp8((unsigned)u, false);
}
#else
__device__ inline floatx2 fp8pair(unsigned short u) {
    __hip_fp8_e4m3 a, b;
    a.__x = (__hip_fp8_storage_t)(u & 0xff);
    b.__x = (__hip_fp8_storage_t)(u >> 8);
    floatx2 r; r.x = (float)a; r.y = (float)b; return r;
}
#endif
__device__ inline unsigned char f2fp8(float f) {
    __hip_fp8_e4m3 q(f); return (unsigned char)q.__x;
}

// ---------------- utility ----------------

__global__ void copy_kernel(const float4* __restrict__ src, float4* __restrict__ dst, int n4) {
    int tid = blockIdx.x * blockDim.x + threadIdx.x;
    int stride = gridDim.x * blockDim.x;
    for (int i = tid; i < n4; i += stride) dst[i] = src[i];
}

// ---------------- binned CSR build ----------------

__global__ void binhist_kernel(const int* __restrict__ dst, int* __restrict__ binCnt,
                               int E, int NB) {
    __shared__ int h[MAXNB];
    for (int i = threadIdx.x; i < NB; i += blockDim.x) h[i] = 0;
    __syncthreads();
    int tid = blockIdx.x * blockDim.x + threadIdx.x;
    int stride = gridDim.x * blockDim.x;
    for (int e = tid; e < E; e += stride) atomicAdd(&h[dst[e] >> 8], 1);
    __syncthreads();
    for (int i = threadIdx.x; i < NB; i += blockDim.x) {
        int v = h[i];
        if (v) atomicAdd(&binCnt[i], v);
    }
}

__global__ void binscan_kernel(const int* __restrict__ binCnt, int* __restrict__ binBase,
                               int* __restrict__ binCursor, int* __restrict__ rowptr,
                               int NB, int N, int E) {
    int lane = threadIdx.x;
    int running = 0;
    for (int c = 0; c * 64 < NB; ++c) {
        int idx = c * 64 + lane;
        int v = (idx < NB) ? binCnt[idx] : 0;
        int inc = v;
        for (int off = 1; off < 64; off <<= 1) {
            int u = __shfl_up(inc, off);
            if (lane >= off) inc += u;
        }
        int excl = running + inc - v;
        if (idx < NB) { binBase[idx] = excl; binCursor[idx] = excl; }
        running += __shfl(inc, 63);
    }
    if (lane == 0) { binBase[NB] = E; rowptr[N] = E; }
}

__launch_bounds__(256, 4)
__global__ void phaseB_kernel(const int* __restrict__ src, const int* __restrict__ dst,
                              int* __restrict__ binCursor, int2* __restrict__ etmp,
                              int E, int NB) {
    __shared__ int hist[MAXNB], sbase[MAXNB], lcnt[MAXNB], adj[MAXNB];
    __shared__ int2 rb[CHUNK];
    int t = threadIdx.x, lane = t & 63, wv = t >> 6;
    int base = blockIdx.x * CHUNK;
    int ne = min(CHUNK, E - base);
    for (int i = t; i < NB; i += 256) { hist[i] = 0; lcnt[i] = 0; }
    __syncthreads();
    const int PT = CHUNK / 256;
    int rs[PT], rd[PT];
#pragma unroll
    for (int i = 0; i < PT; ++i) {
        int idx = i * 256 + t;
        if (idx < ne) {
            rs[i] = src[base + idx];
            rd[i] = dst[base + idx];
            atomicAdd(&hist[rd[i] >> 8], 1);
        } else rd[i] = -1;
    }
    __syncthreads();
    if (wv == 0) {
        int running = 0;
        for (int c = 0; c * 64 < NB; ++c) {
            int idx = c * 64 + lane;
            int v = (idx < NB) ? hist[idx] : 0;
            int inc = v;
            for (int off = 1; off < 64; off <<= 1) {
                int u = __shfl_up(inc, off);
                if (lane >= off) inc += u;
            }
            if (idx < NB) sbase[idx] = running + inc - v;
            running += __shfl(inc, 63);
        }
    }
    __syncthreads();
    for (int bIdx = t; bIdx < NB; bIdx += 256) {
        int hcount = hist[bIdx];
        if (hcount) {
            int g = atomicAdd(&binCursor[bIdx], hcount);
            adj[bIdx] = g - sbase[bIdx];
        }
    }
    __syncthreads();
#pragma unroll
    for (int i = 0; i < PT; ++i) {
        if (rd[i] >= 0) {
            int bb = rd[i] >> 8;
            int off = atomicAdd(&lcnt[bb], 1);
            rb[sbase[bb] + off] = make_int2(rs[i], rd[i]);
        }
    }
    __syncthreads();
    for (int p = t; p < ne; p += 256) {
        int2 v = rb[p];
        etmp[p + adj[v.y >> 8]] = v;
    }
}

__global__ void bin2csr_kernel(const int2* __restrict__ etmp, const int* __restrict__ binBase,
                               int* __restrict__ rowptr, float* __restrict__ dinv,
                               int* __restrict__ esrc, int N) {
    __shared__ int hist[256], lcur[256], wsum[4];
    int t = threadIdx.x, b = blockIdx.x;
    hist[t] = 0;
    __syncthreads();
    int bb = binBase[b], ne = binBase[b + 1] - bb;
    for (int i = t; i < ne; i += 256) atomicAdd(&hist[etmp[bb + i].y & 255], 1);
    __syncthreads();
    int lane = t & 63, wv = t >> 6;
    int v = hist[t];
    int inc = v;
    for (int off = 1; off < 64; off <<= 1) {
        int u = __shfl_up(inc, off);
        if (lane >= off) inc += u;
    }
    if (lane == 63) wsum[wv] = inc;
    __syncthreads();
    int woff = 0;
    for (int i = 0; i < wv; ++i) woff += wsum[i];
    int excl = woff + inc - v;
    int node = b * 256 + t;
    if (node < N) {
        rowptr[node] = bb + excl;
        dinv[node] = rsqrtf((float)(v + 1));   // +1 self loop
    }
    lcur[t] = excl;
    __syncthreads();
    for (int i = t; i < ne; i += 256) {
        int2 e = etmp[bb + i];
        int p = atomicAdd(&lcur[e.y & 255], 1);
        esrc[bb + p] = e.x;
    }
}

// ---------------- layer kernels ----------------

// Apb[N,64](fp8 e4m3) = (X[N,128] @ W1) * dinv[row]; W1 column in 128 regs.
// 2 rows per wave per iteration, next-pair global prefetch.
__launch_bounds__(256, 2)
__global__ void rowgemm_kernel(const float* __restrict__ X, const float* __restrict__ W,
                               const float* __restrict__ dinv,
                               unsigned char* __restrict__ Apb, int N) {
    __shared__ float xbuf[4][2][128];
    int lane = threadIdx.x & 63;
    int wv = threadIdx.x >> 6;
    float w[128];
#pragma unroll
    for (int k = 0; k < 128; ++k) w[k] = W[k * 64 + lane];
    int wave = (blockIdx.x * blockDim.x + threadIdx.x) >> 6;
    int nw = (gridDim.x * blockDim.x) >> 6;
    const float4* xa4 = (const float4*)xbuf[wv][0];
    const float4* xb4 = (const float4*)xbuf[wv][1];
    int v = wave * 2;
    int stride = nw * 2;
    float2 x2a = make_float2(0.f, 0.f), x2b = make_float2(0.f, 0.f);
    if (v < N)     x2a = *(const float2*)(X + (size_t)v * 128 + lane * 2);
    if (v + 1 < N) x2b = *(const float2*)(X + (size_t)(v + 1) * 128 + lane * 2);
    while (v < N) {
        *(float2*)&xbuf[wv][0][lane * 2] = x2a;
        *(float2*)&xbuf[wv][1][lane * 2] = x2b;
        int vn = v + stride;
        float2 xna = make_float2(0.f, 0.f), xnb = make_float2(0.f, 0.f);
        if (vn < N)     xna = *(const float2*)(X + (size_t)vn * 128 + lane * 2);
        if (vn + 1 < N) xnb = *(const float2*)(X + (size_t)(vn + 1) * 128 + lane * 2);
        float dva = dinv[v];
        float dvb = (v + 1 < N) ? dinv[v + 1] : 0.f;
        asm volatile("s_waitcnt lgkmcnt(0)" ::: "memory");
        float acca = 0.f, accb = 0.f;
#pragma unroll
        for (int k4 = 0; k4 < 32; ++k4) {
            float4 va = xa4[k4];
            float4 vb = xb4[k4];
            float w0 = w[4 * k4 + 0], w1 = w[4 * k4 + 1];
            float w2 = w[4 * k4 + 2], w3 = w[4 * k4 + 3];
            acca += va.x * w0 + va.y * w1 + va.z * w2 + va.w * w3;
            accb += vb.x * w0 + vb.y * w1 + vb.z * w2 + vb.w * w3;
        }
        Apb[(size_t)v * 64 + lane] = f2fp8(acca * dva);
        if (v + 1 < N) Apb[(size_t)(v + 1) * 64 + lane] = f2fp8(accb * dvb);
        asm volatile("s_waitcnt lgkmcnt(0)" ::: "memory");
        v = vn; x2a = xna; x2b = xnb;
    }
}

// Wave per node, scalar-indexed paired gather on fp8 rows (64B = 1 line/edge):
// half h handles edge 2j+h, lane loads ushort = 2 fp8 cols, HW packed decode,
// unroll 4. Self-row/dinv hoisted ahead of loop. Fold shfl_xor(32).
// Then h = relu(...), dual-accumulator fused GEMM2 -> A2pb (40B rows).
__launch_bounds__(256, 2)
__global__ void layer_mid_kernel(const unsigned char* __restrict__ Apb,
                                 const int* __restrict__ esrc,
                                 const int* __restrict__ rowptr, const float* __restrict__ dinv,
                                 const float* __restrict__ W2, const float* __restrict__ b1,
                                 unsigned char* __restrict__ A2pb, int N) {
    __shared__ float hbuf[4][64];
    int lane = threadIdx.x & 63;
    int wv = threadIdx.x >> 6;
    int pl = lane & 31, half = lane >> 5;
    int cidx = lane < 40 ? lane : 0;
    float w2[64];
#pragma unroll
    for (int k = 0; k < 64; ++k) w2[k] = W2[k * 40 + cidx];
    float2 bias2 = ((const float2*)b1)[pl];
    int gtid = blockIdx.x * blockDim.x + threadIdx.x;
    int wave = gtid >> 6;
    int nw = (gridDim.x * blockDim.x) >> 6;
    const float4* hb4 = (const float4*)hbuf[wv];
    for (int v = wave; v < N; v += nw) {
        int i0 = __builtin_amdgcn_readfirstlane(rowptr[v]);
        int i1 = __builtin_amdgcn_readfirstlane(rowptr[v + 1]);
        // hoisted: self row + dinv load overlap the gather loop
        unsigned short us = *(const unsigned short*)(Apb + (size_t)v * 64 + pl * 2);
        float dv = dinv[v];
        float ax = 0.f, ay = 0.f;
        int j = i0;
#pragma unroll 4
        for (; j + 2 <= i1; j += 2) {
            int s0 = esrc[j];                    // wave-uniform -> s_load
            int s1 = esrc[j + 1];
            int s = half ? s1 : s0;              // one cndmask
            unsigned short u = *(const unsigned short*)(Apb + (size_t)s * 64 + pl * 2);
            floatx2 f = fp8pair(u);
            ax += f.x; ay += f.y;
        }
        if (j < i1) {
            int s0 = esrc[j];
            if (half == 0) {
                unsigned short u = *(const unsigned short*)(Apb + (size_t)s0 * 64 + pl * 2);
                floatx2 f = fp8pair(u);
                ax += f.x; ay += f.y;
            }
        }
        ax += __shfl_xor(ax, 32);
        ay += __shfl_xor(ay, 32);
        floatx2 fs = fp8pair(us);
        float h0 = dv * (ax + fs.x * dv) + bias2.x;
        float h1 = dv * (ay + fs.y * dv) + bias2.y;
        h0 = h0 > 0.f ? h0 : 0.f;
        h1 = h1 > 0.f ? h1 : 0.f;
        if (half == 0) *(float2*)&hbuf[wv][pl * 2] = make_float2(h0, h1);
        asm volatile("s_waitcnt lgkmcnt(0)" ::: "memory");
        float a2a = 0.f, a2b = 0.f;          // dual accumulators: 2 FMA chains
#pragma unroll
        for (int k4 = 0; k4 < 8; ++k4) {
            float4 hv0 = hb4[2 * k4];
            float4 hv1 = hb4[2 * k4 + 1];
            a2a += hv0.x * w2[8 * k4 + 0] + hv0.y * w2[8 * k4 + 1]
                 + hv0.z * w2[8 * k4 + 2] + hv0.w * w2[8 * k4 + 3];
            a2b += hv1.x * w2[8 * k4 + 4] + hv1.y * w2[8 * k4 + 5]
                 + hv1.z * w2[8 * k4 + 6] + hv1.w * w2[8 * k4 + 7];
        }
        float a2 = a2a + a2b;
        if (lane < 40) A2pb[(size_t)v * 40 + lane] = f2fp8(a2 * dv);
        asm volatile("s_waitcnt lgkmcnt(0)" ::: "memory");
    }
}

// Wave per node, scalar-indexed paired gather over 40 fp8 cols (pl<20 active),
// HW packed decode, unroll 4; z = dinv*(sum + A2p[v]*dinv) + b2,
// out = log_softmax(softmax(z)), paired layout.
__global__ void layer_out_kernel(const unsigned char* __restrict__ A2pb,
                                 const int* __restrict__ esrc,
                                 const int* __restrict__ rowptr, const float* __restrict__ dinv,
                                 const float* __restrict__ b2, float* __restrict__ out, int N) {
    int gtid = blockIdx.x * blockDim.x + threadIdx.x;
    int wave = gtid >> 6, lane = threadIdx.x & 63;
    int pl = lane & 31, half = lane >> 5;
    bool pact = pl < 20;
    int plc = pact ? pl : 0;
    float2 b2v = ((const float2*)b2)[plc];
    int nw = (gridDim.x * blockDim.x) >> 6;
    for (int v = wave; v < N; v += nw) {
        int i0 = __builtin_amdgcn_readfirstlane(rowptr[v]);
        int i1 = __builtin_amdgcn_readfirstlane(rowptr[v + 1]);
        float ax = 0.f, ay = 0.f;
        int j = i0;
#pragma unroll 4
        for (; j + 2 <= i1; j += 2) {
            int s0 = esrc[j];
            int s1 = esrc[j + 1];
            int s = half ? s1 : s0;
            if (pact) {
                unsigned short u = *(const unsigned short*)(A2pb + (size_t)s * 40 + pl * 2);
                floatx2 f = fp8pair(u);
                ax += f.x; ay += f.y;
            }
        }
        if (j < i1) {
            int s0 = esrc[j];
            if (half == 0 && pact) {
                unsigned short u = *(const unsigned short*)(A2pb + (size_t)s0 * 40 + pl * 2);
                floatx2 f = fp8pair(u);
                ax += f.x; ay += f.y;
            }
        }
        ax += __shfl_xor(ax, 32);
        ay += __shfl_xor(ay, 32);
        float dv = dinv[v];
        float z0 = -INFINITY, z1 = -INFINITY;
        if (pact) {
            unsigned short us = *(const unsigned short*)(A2pb + (size_t)v * 40 + pl * 2);
            floatx2 fs = fp8pair(us);
            z0 = dv * (ax + fs.x * dv) + b2v.x;
            z1 = dv * (ay + fs.y * dv) + b2v.y;
        }
        float m = fmaxf(z0, z1);
        for (int off = 16; off; off >>= 1) m = fmaxf(m, __shfl_xor(m, off));
        float e0 = pact ? expf(z0 - m) : 0.f;
        float e1 = pact ? expf(z1 - m) : 0.f;
        float s = e0 + e1;
        for (int off = 16; off; off >>= 1) s += __shfl_xor(s, off);
        float p0 = e0 / s, p1 = e1 / s;
        float m2 = pact ? fmaxf(p0, p1) : -INFINITY;
        for (int off = 16; off; off >>= 1) m2 = fmaxf(m2, __shfl_xor(m2, off));
        float q0 = pact ? expf(p0 - m2) : 0.f;
        float q1 = pact ? expf(p1 - m2) : 0.f;
        float s2 = q0 + q1;
        for (int off = 16; off; off >>= 1) s2 += __shfl_xor(s2, off);
        if (pact && half == 0) {
            float ls2 = logf(s2);
            *(float2*)&out[(size_t)v * 40 + pl * 2] =
                make_float2((p0 - m2) - ls2, (p1 - m2) - ls2);
        }
    }
}

// ---------------- launch ----------------

extern "C" void kernel_launch(void* const* d_in, const int* in_sizes, int n_in,
                              void* d_out, int out_size, void* d_ws, size_t ws_size,
                              hipStream_t stream) {
    const float* x_in  = (const float*)d_in[0];
    const int*   ei    = (const int*)d_in[1];
    const float* W1_in = (const float*)d_in[2];
    const float* b1_in = (const float*)d_in[3];
    const float* W2_in = (const float*)d_in[4];
    const float* b2_in = (const float*)d_in[5];
    float* out = (float*)d_out;

    int N = in_sizes[0] / 128;
    int E = in_sizes[1] / 2;
    const int* src = ei;
    const int* dst = ei + E;
    int NB = (N + 255) >> 8;            // 256-node bins

    char* ws = (char*)d_ws;
    size_t o = 0;
    auto alloc = [&](size_t bytes) { void* p = ws + o; o += (bytes + 255) & ~(size_t)255; return p; };
    int*   binCnt    = (int*)alloc((size_t)MAXNB * 4);
    int*   binBase   = (int*)alloc(((size_t)MAXNB + 1) * 4);
    int*   binCursor = (int*)alloc((size_t)MAXNB * 4);
    float* dinv      = (float*)alloc((size_t)N * 4);
    int*   rowptr    = (int*)alloc(((size_t)N + 1) * 4);
    int2*  etmp      = (int2*)alloc((size_t)E * 8);
    int*   esrc      = (int*)alloc((size_t)E * 4);
    unsigned char* Apb  = (unsigned char*)alloc((size_t)N * 64);
    unsigned char* A2pb = (unsigned char*)alloc((size_t)N * 40);
    float* W1c = (float*)alloc(128 * 64 * 4);
    float* W2c = (float*)alloc(64 * 40 * 4);
    float* b1c = (float*)alloc(64 * 4);
    float* b2c = (float*)alloc(40 * 4);

    // stage small fp32 params
    copy_kernel<<<8, 256, 0, stream>>>((const float4*)W1_in, (float4*)W1c, 128 * 64 / 4);
    copy_kernel<<<4, 256, 0, stream>>>((const float4*)W2_in, (float4*)W2c, 64 * 40 / 4);
    copy_kernel<<<1, 64, 0, stream>>>((const float4*)b1_in, (float4*)b1c, 16);
    copy_kernel<<<1, 64, 0, stream>>>((const float4*)b2_in, (float4*)b2c, 10);

    // binned CSR build
    hipMemsetAsync(binCnt, 0, (size_t)MAXNB * 4, stream);
    binhist_kernel<<<512, 256, 0, stream>>>(dst, binCnt, E, NB);
    binscan_kernel<<<1, 64, 0, stream>>>(binCnt, binBase, binCursor, rowptr, NB, N, E);
    phaseB_kernel<<<(E + CHUNK - 1) / CHUNK, 256, 0, stream>>>(src, dst, binCursor, etmp, E, NB);
    bin2csr_kernel<<<NB, 256, 0, stream>>>(etmp, binBase, rowptr, dinv, esrc, N);

    // layers
    rowgemm_kernel<<<4096, 256, 0, stream>>>(x_in, W1c, dinv, Apb, N);
    layer_mid_kernel<<<2048, 256, 0, stream>>>(Apb, esrc, rowptr, dinv, W2c, b1c, A2pb, N);
    layer_out_kernel<<<2048, 256, 0, stream>>>(A2pb, esrc, rowptr, dinv, b2c, out, N);
}

// Round 19
// 239.797 us; speedup vs baseline: 1.1309x; 1.0141x over previous
//
#include <hip/hip_runtime.h>
#include <hip/hip_fp8.h>
#include <math.h>

#define MAXNB 512
#define CHUNK 4096

typedef float floatx2 __attribute__((ext_vector_type(2)));

#if __has_builtin(__builtin_amdgcn_cvt_pk_f32_fp8)
__device__ inline floatx2 fp8pair(unsigned short u) {
    return __builtin_amdgcn_cvt_pk_f32_fp8((unsigned)u, false);
}
#else
__device__ inline floatx2 fp8pair(unsigned short u) {
    __hip_fp8_e4m3 a, b;
    a.__x = (__hip_fp8_storage_t)(u & 0xff);
    b.__x = (__hip_fp8_storage_t)(u >> 8);
    floatx2 r; r.x = (float)a; r.y = (float)b; return r;
}
#endif
__device__ inline unsigned char f2fp8(float f) {
    __hip_fp8_e4m3 q(f); return (unsigned char)q.__x;
}

// ---------------- utility ----------------

__global__ void copy_kernel(const float4* __restrict__ src, float4* __restrict__ dst, int n4) {
    int tid = blockIdx.x * blockDim.x + threadIdx.x;
    int stride = gridDim.x * blockDim.x;
    for (int i = tid; i < n4; i += stride) dst[i] = src[i];
}

// ---------------- binned CSR build ----------------

__global__ void binhist_kernel(const int* __restrict__ dst, int* __restrict__ binCnt,
                               int E, int NB) {
    __shared__ int h[MAXNB];
    for (int i = threadIdx.x; i < NB; i += blockDim.x) h[i] = 0;
    __syncthreads();
    int tid = blockIdx.x * blockDim.x + threadIdx.x;
    int stride = gridDim.x * blockDim.x;
    for (int e = tid; e < E; e += stride) atomicAdd(&h[dst[e] >> 8], 1);
    __syncthreads();
    for (int i = threadIdx.x; i < NB; i += blockDim.x) {
        int v = h[i];
        if (v) atomicAdd(&binCnt[i], v);
    }
}

__global__ void binscan_kernel(const int* __restrict__ binCnt, int* __restrict__ binBase,
                               int* __restrict__ binCursor, int* __restrict__ rowptr,
                               int NB, int N, int E) {
    int lane = threadIdx.x;
    int running = 0;
    for (int c = 0; c * 64 < NB; ++c) {
        int idx = c * 64 + lane;
        int v = (idx < NB) ? binCnt[idx] : 0;
        int inc = v;
        for (int off = 1; off < 64; off <<= 1) {
            int u = __shfl_up(inc, off);
            if (lane >= off) inc += u;
        }
        int excl = running + inc - v;
        if (idx < NB) { binBase[idx] = excl; binCursor[idx] = excl; }
        running += __shfl(inc, 63);
    }
    if (lane == 0) { binBase[NB] = E; rowptr[N] = E; }
}

// chunk-local LDS bin-sort; etmp packed 4B/edge: src | (dst&255)<<24
__launch_bounds__(256, 4)
__global__ void phaseB_kernel(const int* __restrict__ src, const int* __restrict__ dst,
                              int* __restrict__ binCursor, unsigned* __restrict__ etmp,
                              int E, int NB) {
    __shared__ int hist[MAXNB], sbase[MAXNB], lcnt[MAXNB], adj[MAXNB];
    __shared__ int2 rb[CHUNK];
    int t = threadIdx.x, lane = t & 63, wv = t >> 6;
    int base = blockIdx.x * CHUNK;
    int ne = min(CHUNK, E - base);
    for (int i = t; i < NB; i += 256) { hist[i] = 0; lcnt[i] = 0; }
    __syncthreads();
    const int PT = CHUNK / 256;
    int rs[PT], rd[PT];
#pragma unroll
    for (int i = 0; i < PT; ++i) {
        int idx = i * 256 + t;
        if (idx < ne) {
            rs[i] = src[base + idx];
            rd[i] = dst[base + idx];
            atomicAdd(&hist[rd[i] >> 8], 1);
        } else rd[i] = -1;
    }
    __syncthreads();
    if (wv == 0) {
        int running = 0;
        for (int c = 0; c * 64 < NB; ++c) {
            int idx = c * 64 + lane;
            int v = (idx < NB) ? hist[idx] : 0;
            int inc = v;
            for (int off = 1; off < 64; off <<= 1) {
                int u = __shfl_up(inc, off);
                if (lane >= off) inc += u;
            }
            if (idx < NB) sbase[idx] = running + inc - v;
            running += __shfl(inc, 63);
        }
    }
    __syncthreads();
    for (int bIdx = t; bIdx < NB; bIdx += 256) {
        int hcount = hist[bIdx];
        if (hcount) {
            int g = atomicAdd(&binCursor[bIdx], hcount);
            adj[bIdx] = g - sbase[bIdx];
        }
    }
    __syncthreads();
#pragma unroll
    for (int i = 0; i < PT; ++i) {
        if (rd[i] >= 0) {
            int bb = rd[i] >> 8;
            int off = atomicAdd(&lcnt[bb], 1);
            rb[sbase[bb] + off] = make_int2(rs[i], rd[i]);
        }
    }
    __syncthreads();
    for (int p = t; p < ne; p += 256) {
        int2 v = rb[p];
        etmp[p + adj[v.y >> 8]] = (unsigned)v.x | ((unsigned)(v.y & 255) << 24);
    }
}

// block per bin: node histogram -> rowptr + dinv, then node-contiguous esrc.
__global__ void bin2csr_kernel(const unsigned* __restrict__ etmp, const int* __restrict__ binBase,
                               int* __restrict__ rowptr, float* __restrict__ dinv,
                               int* __restrict__ esrc, int N) {
    __shared__ int hist[256], lcur[256], wsum[4];
    int t = threadIdx.x, b = blockIdx.x;
    hist[t] = 0;
    __syncthreads();
    int bb = binBase[b], ne = binBase[b + 1] - bb;
    for (int i = t; i < ne; i += 256) atomicAdd(&hist[etmp[bb + i] >> 24], 1);
    __syncthreads();
    int lane = t & 63, wv = t >> 6;
    int v = hist[t];
    int inc = v;
    for (int off = 1; off < 64; off <<= 1) {
        int u = __shfl_up(inc, off);
        if (lane >= off) inc += u;
    }
    if (lane == 63) wsum[wv] = inc;
    __syncthreads();
    int woff = 0;
    for (int i = 0; i < wv; ++i) woff += wsum[i];
    int excl = woff + inc - v;
    int node = b * 256 + t;
    if (node < N) {
        rowptr[node] = bb + excl;
        dinv[node] = rsqrtf((float)(v + 1));   // +1 self loop
    }
    lcur[t] = excl;
    __syncthreads();
    for (int i = t; i < ne; i += 256) {
        unsigned e = etmp[bb + i];
        int p = atomicAdd(&lcur[e >> 24], 1);
        esrc[bb + p] = (int)(e & 0xFFFFFFu);
    }
}

// ---------------- layer kernels ----------------

// Apb[N,64](fp8 e4m3) = (X[N,128] @ W1) * dinv[row]; W1 column in 128 regs.
// 2 rows per wave per iteration, next-pair global prefetch.
__launch_bounds__(256, 2)
__global__ void rowgemm_kernel(const float* __restrict__ X, const float* __restrict__ W,
                               const float* __restrict__ dinv,
                               unsigned char* __restrict__ Apb, int N) {
    __shared__ float xbuf[4][2][128];
    int lane = threadIdx.x & 63;
    int wv = threadIdx.x >> 6;
    float w[128];
#pragma unroll
    for (int k = 0; k < 128; ++k) w[k] = W[k * 64 + lane];
    int wave = (blockIdx.x * blockDim.x + threadIdx.x) >> 6;
    int nw = (gridDim.x * blockDim.x) >> 6;
    const float4* xa4 = (const float4*)xbuf[wv][0];
    const float4* xb4 = (const float4*)xbuf[wv][1];
    int v = wave * 2;
    int stride = nw * 2;
    float2 x2a = make_float2(0.f, 0.f), x2b = make_float2(0.f, 0.f);
    if (v < N)     x2a = *(const float2*)(X + (size_t)v * 128 + lane * 2);
    if (v + 1 < N) x2b = *(const float2*)(X + (size_t)(v + 1) * 128 + lane * 2);
    while (v < N) {
        *(float2*)&xbuf[wv][0][lane * 2] = x2a;
        *(float2*)&xbuf[wv][1][lane * 2] = x2b;
        int vn = v + stride;
        float2 xna = make_float2(0.f, 0.f), xnb = make_float2(0.f, 0.f);
        if (vn < N)     xna = *(const float2*)(X + (size_t)vn * 128 + lane * 2);
        if (vn + 1 < N) xnb = *(const float2*)(X + (size_t)(vn + 1) * 128 + lane * 2);
        float dva = dinv[v];
        float dvb = (v + 1 < N) ? dinv[v + 1] : 0.f;
        asm volatile("s_waitcnt lgkmcnt(0)" ::: "memory");
        float acca = 0.f, accb = 0.f;
#pragma unroll
        for (int k4 = 0; k4 < 32; ++k4) {
            float4 va = xa4[k4];
            float4 vb = xb4[k4];
            float w0 = w[4 * k4 + 0], w1 = w[4 * k4 + 1];
            float w2 = w[4 * k4 + 2], w3 = w[4 * k4 + 3];
            acca += va.x * w0 + va.y * w1 + va.z * w2 + va.w * w3;
            accb += vb.x * w0 + vb.y * w1 + vb.z * w2 + vb.w * w3;
        }
        Apb[(size_t)v * 64 + lane] = f2fp8(acca * dva);
        if (v + 1 < N) Apb[(size_t)(v + 1) * 64 + lane] = f2fp8(accb * dvb);
        asm volatile("s_waitcnt lgkmcnt(0)" ::: "memory");
        v = vn; x2a = xna; x2b = xnb;
    }
}

// Wave per node, scalar-indexed paired gather on fp8 rows (64B = 1 line/edge):
// half h handles edge 2j+h, lane loads ushort = 2 fp8 cols, HW packed decode,
// unroll 4. Self-row/dinv hoisted ahead of loop. Fold shfl_xor(32).
// Then h = relu(...), dual-accumulator fused GEMM2 -> A2pb (40B rows).
__launch_bounds__(256, 2)
__global__ void layer_mid_kernel(const unsigned char* __restrict__ Apb,
                                 const int* __restrict__ esrc,
                                 const int* __restrict__ rowptr, const float* __restrict__ dinv,
                                 const float* __restrict__ W2, const float* __restrict__ b1,
                                 unsigned char* __restrict__ A2pb, int N) {
    __shared__ float hbuf[4][64];
    int lane = threadIdx.x & 63;
    int wv = threadIdx.x >> 6;
    int pl = lane & 31, half = lane >> 5;
    int cidx = lane < 40 ? lane : 0;
    float w2[64];
#pragma unroll
    for (int k = 0; k < 64; ++k) w2[k] = W2[k * 40 + cidx];
    float2 bias2 = ((const float2*)b1)[pl];
    int gtid = blockIdx.x * blockDim.x + threadIdx.x;
    int wave = gtid >> 6;
    int nw = (gridDim.x * blockDim.x) >> 6;
    const float4* hb4 = (const float4*)hbuf[wv];
    for (int v = wave; v < N; v += nw) {
        int i0 = __builtin_amdgcn_readfirstlane(rowptr[v]);
        int i1 = __builtin_amdgcn_readfirstlane(rowptr[v + 1]);
        // hoisted: self row + dinv load overlap the gather loop
        unsigned short us = *(const unsigned short*)(Apb + (size_t)v * 64 + pl * 2);
        float dv = dinv[v];
        float ax = 0.f, ay = 0.f;
        int j = i0;
#pragma unroll 4
        for (; j + 2 <= i1; j += 2) {
            int s0 = esrc[j];                    // wave-uniform -> s_load
            int s1 = esrc[j + 1];
            int s = half ? s1 : s0;              // one cndmask
            unsigned short u = *(const unsigned short*)(Apb + (size_t)s * 64 + pl * 2);
            floatx2 f = fp8pair(u);
            ax += f.x; ay += f.y;
        }
        if (j < i1) {
            int s0 = esrc[j];
            if (half == 0) {
                unsigned short u = *(const unsigned short*)(Apb + (size_t)s0 * 64 + pl * 2);
                floatx2 f = fp8pair(u);
                ax += f.x; ay += f.y;
            }
        }
        ax += __shfl_xor(ax, 32);
        ay += __shfl_xor(ay, 32);
        floatx2 fs = fp8pair(us);
        float h0 = dv * (ax + fs.x * dv) + bias2.x;
        float h1 = dv * (ay + fs.y * dv) + bias2.y;
        h0 = h0 > 0.f ? h0 : 0.f;
        h1 = h1 > 0.f ? h1 : 0.f;
        if (half == 0) *(float2*)&hbuf[wv][pl * 2] = make_float2(h0, h1);
        asm volatile("s_waitcnt lgkmcnt(0)" ::: "memory");
        float a2a = 0.f, a2b = 0.f;          // dual accumulators: 2 FMA chains
#pragma unroll
        for (int k4 = 0; k4 < 8; ++k4) {
            float4 hv0 = hb4[2 * k4];
            float4 hv1 = hb4[2 * k4 + 1];
            a2a += hv0.x * w2[8 * k4 + 0] + hv0.y * w2[8 * k4 + 1]
                 + hv0.z * w2[8 * k4 + 2] + hv0.w * w2[8 * k4 + 3];
            a2b += hv1.x * w2[8 * k4 + 4] + hv1.y * w2[8 * k4 + 5]
                 + hv1.z * w2[8 * k4 + 6] + hv1.w * w2[8 * k4 + 7];
        }
        float a2 = a2a + a2b;
        if (lane < 40) A2pb[(size_t)v * 40 + lane] = f2fp8(a2 * dv);
        asm volatile("s_waitcnt lgkmcnt(0)" ::: "memory");
    }
}

// Wave per node, scalar-indexed paired gather over 40 fp8 cols (pl<20 active),
// HW packed decode, unroll 4, self-row/dinv hoisted;
// z = dinv*(sum + A2p[v]*dinv) + b2, out = log_softmax(softmax(z)).
__global__ void layer_out_kernel(const unsigned char* __restrict__ A2pb,
                                 const int* __restrict__ esrc,
                                 const int* __restrict__ rowptr, const float* __restrict__ dinv,
                                 const float* __restrict__ b2, float* __restrict__ out, int N) {
    int gtid = blockIdx.x * blockDim.x + threadIdx.x;
    int wave = gtid >> 6, lane = threadIdx.x & 63;
    int pl = lane & 31, half = lane >> 5;
    bool pact = pl < 20;
    int plc = pact ? pl : 0;
    float2 b2v = ((const float2*)b2)[plc];
    int nw = (gridDim.x * blockDim.x) >> 6;
    for (int v = wave; v < N; v += nw) {
        int i0 = __builtin_amdgcn_readfirstlane(rowptr[v]);
        int i1 = __builtin_amdgcn_readfirstlane(rowptr[v + 1]);
        // hoisted self-row + dinv
        unsigned short us = pact ? *(const unsigned short*)(A2pb + (size_t)v * 40 + pl * 2) : 0;
        float dv = dinv[v];
        float ax = 0.f, ay = 0.f;
        int j = i0;
#pragma unroll 4
        for (; j + 2 <= i1; j += 2) {
            int s0 = esrc[j];
            int s1 = esrc[j + 1];
            int s = half ? s1 : s0;
            if (pact) {
                unsigned short u = *(const unsigned short*)(A2pb + (size_t)s * 40 + pl * 2);
                floatx2 f = fp8pair(u);
                ax += f.x; ay += f.y;
            }
        }
        if (j < i1) {
            int s0 = esrc[j];
            if (half == 0 && pact) {
                unsigned short u = *(const unsigned short*)(A2pb + (size_t)s0 * 40 + pl * 2);
                floatx2 f = fp8pair(u);
                ax += f.x; ay += f.y;
            }
        }
        ax += __shfl_xor(ax, 32);
        ay += __shfl_xor(ay, 32);
        float z0 = -INFINITY, z1 = -INFINITY;
        if (pact) {
            floatx2 fs = fp8pair(us);
            z0 = dv * (ax + fs.x * dv) + b2v.x;
            z1 = dv * (ay + fs.y * dv) + b2v.y;
        }
        float m = fmaxf(z0, z1);
        for (int off = 16; off; off >>= 1) m = fmaxf(m, __shfl_xor(m, off));
        float e0 = pact ? expf(z0 - m) : 0.f;
        float e1 = pact ? expf(z1 - m) : 0.f;
        float s = e0 + e1;
        for (int off = 16; off; off >>= 1) s += __shfl_xor(s, off);
        float p0 = e0 / s, p1 = e1 / s;
        float m2 = pact ? fmaxf(p0, p1) : -INFINITY;
        for (int off = 16; off; off >>= 1) m2 = fmaxf(m2, __shfl_xor(m2, off));
        float q0 = pact ? expf(p0 - m2) : 0.f;
        float q1 = pact ? expf(p1 - m2) : 0.f;
        float s2 = q0 + q1;
        for (int off = 16; off; off >>= 1) s2 += __shfl_xor(s2, off);
        if (pact && half == 0) {
            float ls2 = logf(s2);
            *(float2*)&out[(size_t)v * 40 + pl * 2] =
                make_float2((p0 - m2) - ls2, (p1 - m2) - ls2);
        }
    }
}

// ---------------- launch ----------------

extern "C" void kernel_launch(void* const* d_in, const int* in_sizes, int n_in,
                              void* d_out, int out_size, void* d_ws, size_t ws_size,
                              hipStream_t stream) {
    const float* x_in  = (const float*)d_in[0];
    const int*   ei    = (const int*)d_in[1];
    const float* W1_in = (const float*)d_in[2];
    const float* b1_in = (const float*)d_in[3];
    const float* W2_in = (const float*)d_in[4];
    const float* b2_in = (const float*)d_in[5];
    float* out = (float*)d_out;

    int N = in_sizes[0] / 128;
    int E = in_sizes[1] / 2;
    const int* src = ei;
    const int* dst = ei + E;
    int NB = (N + 255) >> 8;            // 256-node bins

    char* ws = (char*)d_ws;
    size_t o = 0;
    auto alloc = [&](size_t bytes) { void* p = ws + o; o += (bytes + 255) & ~(size_t)255; return p; };
    int*      binCnt    = (int*)alloc((size_t)MAXNB * 4);
    int*      binBase   = (int*)alloc(((size_t)MAXNB + 1) * 4);
    int*      binCursor = (int*)alloc((size_t)MAXNB * 4);
    float*    dinv      = (float*)alloc((size_t)N * 4);
    int*      rowptr    = (int*)alloc(((size_t)N + 1) * 4);
    unsigned* etmp      = (unsigned*)alloc((size_t)E * 4);   // packed: src | (dst&255)<<24
    int*      esrc      = (int*)alloc((size_t)E * 4);
    unsigned char* Apb  = (unsigned char*)alloc((size_t)N * 64);
    unsigned char* A2pb = (unsigned char*)alloc((size_t)N * 40);
    float* W1c = (float*)alloc(128 * 64 * 4);
    float* W2c = (float*)alloc(64 * 40 * 4);
    float* b1c = (float*)alloc(64 * 4);
    float* b2c = (float*)alloc(40 * 4);

    // stage small fp32 params
    copy_kernel<<<8, 256, 0, stream>>>((const float4*)W1_in, (float4*)W1c, 128 * 64 / 4);
    copy_kernel<<<4, 256, 0, stream>>>((const float4*)W2_in, (float4*)W2c, 64 * 40 / 4);
    copy_kernel<<<1, 64, 0, stream>>>((const float4*)b1_in, (float4*)b1c, 16);
    copy_kernel<<<1, 64, 0, stream>>>((const float4*)b2_in, (float4*)b2c, 10);

    // binned CSR build
    hipMemsetAsync(binCnt, 0, (size_t)MAXNB * 4, stream);
    binhist_kernel<<<512, 256, 0, stream>>>(dst, binCnt, E, NB);
    binscan_kernel<<<1, 64, 0, stream>>>(binCnt, binBase, binCursor, rowptr, NB, N, E);
    phaseB_kernel<<<(E + CHUNK - 1) / CHUNK, 256, 0, stream>>>(src, dst, binCursor, etmp, E, NB);
    bin2csr_kernel<<<NB, 256, 0, stream>>>(etmp, binBase, rowptr, dinv, esrc, N);

    // layers
    rowgemm_kernel<<<4096, 256, 0, stream>>>(x_in, W1c, dinv, Apb, N);
    layer_mid_kernel<<<2048, 256, 0, stream>>>(Apb, esrc, rowptr, dinv, W2c, b1c, A2pb, N);
    layer_out_kernel<<<2048, 256, 0, stream>>>(A2pb, esrc, rowptr, dinv, b2c, out, N);
}